// Round 10
// baseline (189.074 us; speedup 1.0000x reference)
//
#include <hip/hip_runtime.h>

#define B_ 16
#define C_ 256
#define L_ 2048

using short8 = __attribute__((ext_vector_type(8))) short;
using f32x4  = __attribute__((ext_vector_type(4))) float;
typedef unsigned int uint;

__device__ __forceinline__ unsigned short f2bf(float f) {
  unsigned u = __float_as_uint(f);
  return (unsigned short)((u + 0x7FFFu + ((u >> 16) & 1u)) >> 16);
}

__device__ __forceinline__ void gload16(const void* src, void* dst) {
  __builtin_amdgcn_global_load_lds(
      (const __attribute__((address_space(1))) unsigned int*)src,
      (__attribute__((address_space(3))) unsigned int*)dst, 16, 0, 0);
}

// ---------------- kernel 0: convert weights fp32 -> bf16 ----------------
__global__ __launch_bounds__(256) void convert_w(const float* __restrict__ wt,
                                                 const float* __restrict__ wp,
                                                 const float* __restrict__ wg,
                                                 unsigned short* __restrict__ dst) {
  int i = blockIdx.x * 256 + threadIdx.x;
  dst[i]          = f2bf(wt[i]);
  dst[65536 + i]  = f2bf(wp[i]);
  dst[131072 + i] = f2bf(wg[i]);
}

// ---------------- kernel 1: fused QKV projection (single pass over x) ----------------
__global__ __launch_bounds__(256, 2) void proj_kernel(
    const float* __restrict__ x, const unsigned short* __restrict__ wbf,
    const float* __restrict__ bth, const float* __restrict__ bph,
    const float* __restrict__ bg,
    unsigned short* __restrict__ qT, unsigned short* __restrict__ kT,
    unsigned short* __restrict__ vv)
{
  const int tid  = threadIdx.x;
  const int w    = tid >> 6;
  const int lane = tid & 63;
  const int r    = lane & 15;
  const int g    = lane >> 4;
  const int l0   = blockIdx.x * 64;
  const int b    = blockIdx.y;

  __shared__ unsigned short xs[64 * 256];   // x^T tile [l][c], swizzled (32 KB)
  __shared__ unsigned short wsd[256 * 64];  // W slice [o][c64], swizzled (32 KB)

#pragma unroll
  for (int it = 0; it < 64; ++it) {
    int l = (tid & 15) + 16 * (it & 3);
    int c = (tid >> 4) + 16 * (it >> 2);
    float xvv = x[((size_t)b * C_ + c) * L_ + l0 + l];
    xs[l * 256 + (((c >> 3) ^ (l & 7)) << 3) + (c & 7)] = f2bf(xvv);
  }

  f32x4 acc[4][4];
  for (int p = 0; p < 3; ++p) {
    const unsigned short* wsrc = wbf + p * 65536;
#pragma unroll
    for (int mi = 0; mi < 4; ++mi)
#pragma unroll
      for (int ni = 0; ni < 4; ++ni) acc[mi][ni] = f32x4{0.f, 0.f, 0.f, 0.f};

    for (int ks = 0; ks < 4; ++ks) {
      __syncthreads();
#pragma unroll
      for (int it = 0; it < 8; ++it) {
        int o  = it * 32 + (tid >> 3);
        int cs = tid & 7;
        gload16(wsrc + o * C_ + ks * 64 + ((cs ^ (o & 7)) << 3),
                (void*)(wsd + (size_t)(it * 256 + w * 64) * 8));
      }
      __syncthreads();

#pragma unroll
      for (int kk2 = 0; kk2 < 2; ++kk2) {
        short8 xf[4], wf[4];
#pragma unroll
        for (int i = 0; i < 4; ++i) {
          int lrow = 16 * i + r;
          xf[i] = *(const short8*)(xs + lrow * 256 +
                                   (((8 * ks + 4 * kk2 + g) ^ (lrow & 7)) << 3));
          int orow = 64 * w + 16 * i + r;
          wf[i] = *(const short8*)(wsd + orow * 64 + (((kk2 * 4 + g) ^ (orow & 7)) << 3));
        }
        if (p < 2) {
#pragma unroll
          for (int mi = 0; mi < 4; ++mi)
#pragma unroll
            for (int ni = 0; ni < 4; ++ni)
              acc[mi][ni] = __builtin_amdgcn_mfma_f32_16x16x32_bf16(xf[mi], wf[ni], acc[mi][ni], 0, 0, 0);
        } else {
#pragma unroll
          for (int mi = 0; mi < 4; ++mi)
#pragma unroll
            for (int ni = 0; ni < 4; ++ni)
              acc[mi][ni] = __builtin_amdgcn_mfma_f32_16x16x32_bf16(wf[mi], xf[ni], acc[mi][ni], 0, 0, 0);
        }
      }
    }

    if (p < 2) {
      unsigned short* dst = (p == 0) ? qT : kT;
      const float* bias   = (p == 0) ? bth : bph;
      const float scale   = (p == 0) ? 0.09016844005556021f : 1.0f;  // log2e/16
#pragma unroll
      for (int ni = 0; ni < 4; ++ni) {
        int o    = 64 * w + 16 * ni + r;
        float bv = bias[o];
#pragma unroll
        for (int mi = 0; mi < 4; ++mi)
#pragma unroll
          for (int rr = 0; rr < 4; ++rr) {
            int l = l0 + 16 * mi + 4 * g + rr;
            dst[((size_t)b * L_ + l) * C_ + o] = f2bf((acc[mi][ni][rr] + bv) * scale);
          }
      }
    } else {
#pragma unroll
      for (int mi = 0; mi < 4; ++mi)
#pragma unroll
        for (int rr = 0; rr < 4; ++rr) {
          int o    = 64 * w + 16 * mi + 4 * g + rr;
          float bv = bg[o];
#pragma unroll
          for (int ni = 0; ni < 4; ++ni) {
            int l = l0 + 16 * ni + r;
            vv[((size_t)b * C_ + o) * L_ + l] = f2bf(acc[mi][ni][rr] + bv);
          }
        }
    }
  }
}

// ---------------- kernel 2: flash attention, 16x16 MFMA, occupancy-first ----------------
// 4 waves, wave w owns q-rows i0+16w..+15. Swapped QK^T: sacc = mfma(K,Q) -> lane r = i,
// regs = j -> P j-pairs in-lane -> cvt_pk + 4x b64 swizzled writes. V direct from global
// (no staging). Single kls (32KB) staged for t+1 DURING PV(t). LDS 41KB -> 3 blocks/CU,
// __launch_bounds__(256,3) targets <=168 VGPR -> 3 waves/SIMD.
__global__ __launch_bounds__(256, 3) void attn_kernel(
    const unsigned short* __restrict__ qT, const unsigned short* __restrict__ kT,
    const unsigned short* __restrict__ vv,
    const float* __restrict__ x, float* __restrict__ out)
{
  const int tid  = threadIdx.x;
  const int w    = tid >> 6;
  const int lane = tid & 63;
  const int r    = lane & 15;
  const int g    = lane >> 4;

  // XCD-aware swizzle: 512 blocks, 8 XCDs => each XCD owns 2 batches (K/V L2-resident)
  int wg = ((blockIdx.x & 7) << 6) | (blockIdx.x >> 3);
  const int i0 = (wg & 31) * 64;
  const int b  = wg >> 5;

  __shared__ unsigned short kls[64 * 256];   // K tile [j][c], &7-swizzled (32 KB)
  __shared__ unsigned short pls[64 * 64];    // P [i][j], 8B-slot swizzled (8 KB)
  __shared__ float lsums[64];

  const unsigned short* kTb = kT + (size_t)b * L_ * C_;
  const unsigned short* vvb = vv + (size_t)b * C_ * L_;

  // ---- hoisted Q fragments (B-operand: col i = r, k-chunk g) ----
  short8 qf[8];
  const unsigned short* qrow_p = qT + ((size_t)b * L_ + i0 + 16 * w + r) * C_;
#pragma unroll
  for (int kk = 0; kk < 8; ++kk)
    qf[kk] = *(const short8*)(qrow_p + kk * 32 + 8 * g);

  f32x4 oacc[4][4];
#pragma unroll
  for (int mi = 0; mi < 4; ++mi)
#pragma unroll
    for (int nf = 0; nf < 4; ++nf) oacc[mi][nf] = f32x4{0.f, 0.f, 0.f, 0.f};
  float lsum = 0.f;

  // prologue: stage K tile 0
#pragma unroll
  for (int it = 0; it < 8; ++it) {
    int d   = it * 256 + tid;
    int row = d >> 5;
    int cs  = d & 31;
    gload16(kTb + (size_t)row * C_ + ((cs ^ (row & 7)) << 3), (void*)(kls + d * 8));
  }

  for (int jt = 0; jt < 32; ++jt) {
    const int j0 = jt * 64;
    __syncthreads();   // kls(jt) staged (vmcnt drained); prev PV's pls reads done

    // ---- V gathers (oldest vmem this tile; consumed after next barrier) ----
    short8 vfr[2][4];
#pragma unroll
    for (int kk2 = 0; kk2 < 2; ++kk2)
#pragma unroll
      for (int nf = 0; nf < 4; ++nf)
        vfr[kk2][nf] = *(const short8*)(vvb + (size_t)(64 * w + 16 * nf + r) * L_ +
                                        j0 + 32 * kk2 + 8 * g);

    // ---- S' = K Q (swapped): D[col=i=r][row=j=16ni+4g+rr] ----
    f32x4 sacc[4];
#pragma unroll
    for (int ni = 0; ni < 4; ++ni) sacc[ni] = f32x4{0.f, 0.f, 0.f, 0.f};
    __builtin_amdgcn_s_setprio(1);
#pragma unroll
    for (int kk = 0; kk < 8; ++kk) {
#pragma unroll
      for (int ni = 0; ni < 4; ++ni) {
        int jr = 16 * ni + r;
        short8 kf = *(const short8*)(kls + jr * 256 + (((4 * kk + g) ^ (r & 7)) << 3));
        sacc[ni] = __builtin_amdgcn_mfma_f32_16x16x32_bf16(kf, qf[kk], sacc[ni], 0, 0, 0);
      }
    }
    __builtin_amdgcn_s_setprio(0);

    // ---- P = exp2(S'), in-lane j-pairs -> cvt_pk -> 4x b64 swizzled writes ----
#pragma unroll
    for (int ni = 0; ni < 4; ++ni) {
      float p0, p1, p2, p3;
      asm("v_exp_f32 %0, %1" : "=v"(p0) : "v"(sacc[ni][0]));
      asm("v_exp_f32 %0, %1" : "=v"(p1) : "v"(sacc[ni][1]));
      asm("v_exp_f32 %0, %1" : "=v"(p2) : "v"(sacc[ni][2]));
      asm("v_exp_f32 %0, %1" : "=v"(p3) : "v"(sacc[ni][3]));
      lsum += (p0 + p1) + (p2 + p3);
      uint dlo, dhi;
      asm("v_cvt_pk_bf16_f32 %0, %1, %2" : "=v"(dlo) : "v"(p0), "v"(p1));
      asm("v_cvt_pk_bf16_f32 %0, %1, %2" : "=v"(dhi) : "v"(p2), "v"(p3));
      uint2 d2; d2.x = dlo; d2.y = dhi;
      // P[i = 16w+r][j = 16ni+4g .. +3]: 8B slot s=4ni+g, swizzle s^((r&7)<<1)
      *(uint2*)(pls + (16 * w + r) * 64 + (((4 * ni + g) ^ ((r & 7) << 1)) << 2)) = d2;
    }
    __syncthreads();   // P visible (drains V too - already arrived); kls reads done

    // ---- stage K(t+1) during PV: only correct single-buffer slot; drains next top ----
    if (jt < 31) {
#pragma unroll
      for (int it = 0; it < 8; ++it) {
        int d   = it * 256 + tid;
        int row = d >> 5;
        int cs  = d & 31;
        gload16(kTb + (size_t)(j0 + 64 + row) * C_ + ((cs ^ (row & 7)) << 3),
                (void*)(kls + d * 8));
      }
    }

    // ---- O += P V^T (cooperative: all 64 i via pls, c-slice 64w) ----
    __builtin_amdgcn_s_setprio(1);
#pragma unroll
    for (int kk2 = 0; kk2 < 2; ++kk2) {
      short8 pf[4];
#pragma unroll
      for (int mi = 0; mi < 4; ++mi) {
        int irow = 16 * mi + r;
        pf[mi] = *(const short8*)(pls + irow * 64 + (((4 * kk2 + g) ^ (r & 7)) << 3));
      }
#pragma unroll
      for (int nf = 0; nf < 4; ++nf)
#pragma unroll
        for (int mi = 0; mi < 4; ++mi)
          oacc[mi][nf] = __builtin_amdgcn_mfma_f32_16x16x32_bf16(pf[mi], vfr[kk2][nf], oacc[mi][nf], 0, 0, 0);
    }
    __builtin_amdgcn_s_setprio(0);
  }

  // ---- lsum: lane (r,g) holds partials for j mod 16 in [4g,4g+3]; reduce over g ----
  lsum += __shfl_xor(lsum, 16);
  lsum += __shfl_xor(lsum, 32);
  if (lane < 16) lsums[16 * w + lane] = lsum;
  __syncthreads();

  // ---- epilogue: out = x + O / lsum ----
#pragma unroll
  for (int mi = 0; mi < 4; ++mi) {
    f32x4 ls = *(const f32x4*)(lsums + 16 * mi + 4 * g);
    f32x4 linv;
#pragma unroll
    for (int rr = 0; rr < 4; ++rr) linv[rr] = 1.0f / ls[rr];
#pragma unroll
    for (int nf = 0; nf < 4; ++nf) {
      int c = 64 * w + 16 * nf + r;
      size_t base = ((size_t)b * C_ + c) * L_ + i0 + 16 * mi + 4 * g;
      f32x4 xv = *(const f32x4*)(x + base);
      f32x4 ov;
#pragma unroll
      for (int rr = 0; rr < 4; ++rr)
        ov[rr] = xv[rr] + oacc[mi][nf][rr] * linv[rr];
      *(f32x4*)(out + base) = ov;
    }
  }
}

extern "C" void kernel_launch(void* const* d_in, const int* in_sizes, int n_in,
                              void* d_out, int out_size, void* d_ws, size_t ws_size,
                              hipStream_t stream) {
  (void)in_sizes; (void)n_in; (void)out_size; (void)ws_size;
  const float* x   = (const float*)d_in[0];
  const float* wt  = (const float*)d_in[1];
  const float* bt  = (const float*)d_in[2];
  const float* wp  = (const float*)d_in[3];
  const float* bp  = (const float*)d_in[4];
  const float* wg  = (const float*)d_in[5];
  const float* bgg = (const float*)d_in[6];
  float* out = (float*)d_out;

  char* ws = (char*)d_ws;
  unsigned short* wbf = (unsigned short*)ws;                              // 384 KB
  unsigned short* qT  = (unsigned short*)(ws + 393216);                   // 16 MB
  unsigned short* kT  = (unsigned short*)(ws + 393216 + 16777216);        // 16 MB
  unsigned short* vv  = (unsigned short*)(ws + 393216 + 2 * 16777216);    // 16 MB

  convert_w<<<dim3(256), dim3(256), 0, stream>>>(wt, wp, wg, wbf);
  proj_kernel<<<dim3(32, 16), dim3(256), 0, stream>>>(x, wbf, bt, bp, bgg, qT, kT, vv);
  attn_kernel<<<dim3(512), dim3(256), 0, stream>>>(qT, kT, vv, x, out);
}